// Round 3
// baseline (19491.679 us; speedup 1.0000x reference)
//
#include <hip/hip_runtime.h>
#include <hip/hip_fp16.h>
#include <hip/hip_cooperative_groups.h>

namespace cg = cooperative_groups;

#define T_STEPS 512
#define BATCH   128
#define NID     512
#define DH      512
#define KTOT    1024
#define NG      2048
#define TC      64
#define NCHUNK  (T_STEPS / TC)
#define NWG     256
#define NTHR    256

using f16x8 = __attribute__((ext_vector_type(8))) _Float16;
using f32x4 = __attribute__((ext_vector_type(4))) float;

__device__ __forceinline__ float sigmoid_fast(float x) { return 1.0f / (1.0f + __expf(-x)); }
__device__ __forceinline__ float tanh_fast(float x) {
    float ax = fabsf(x);
    float e  = __expf(2.0f * ax);
    float r  = 1.0f - 2.0f / (e + 1.0f);
    return copysignf(r, x);
}

// ============================ persistent cooperative kernel ============================
// 256 WGs x 256 thr, 1 WG/CU.  Phases: prep -> per chunk { intern GEMM, 64 scan steps }.
// Scan: WG = (row-half rh, col-group cg): 64 batch rows x 16 arranged cols.
// Wr slice resident in registers (16 f16x8 per lane = 64 VGPR).
__global__ __launch_bounds__(NTHR, 1)
void lstm_persist(const float* __restrict__ X,
                  const float* __restrict__ Wf,
                  const float* __restrict__ Wr,
                  const float* __restrict__ bfs,
                  const float* __restrict__ imask,
                  const float* __restrict__ h0,
                  const float* __restrict__ c0,
                  _Float16* __restrict__ WT,    // [2048][1024] arranged (d*4+g, k)
                  float* __restrict__ bfa,      // [2048] arranged bias
                  _Float16* __restrict__ hb,    // [2][128][512] fp16 h double buffer
                  float* __restrict__ cbuf,     // [128][512] f32 c state
                  _Float16* __restrict__ zbuf,  // [TC*128][2048] fp16 intern chunk
                  float* __restrict__ Yout,
                  float* __restrict__ Cout,
                  float* __restrict__ dout)
{
    cg::grid_group grid = cg::this_grid();
    const int tid  = threadIdx.x;
    const int wg   = blockIdx.x;
    const int lane = tid & 63;
    const int wv   = tid >> 6;
    const int l15  = lane & 15;
    const int l4   = lane >> 4;

    __shared__ float zs[4][16][17];

    // ---- phase 0: prep WT (arranged fp16), bfa, h, c ----
    #pragma unroll
    for (int rr = 0; rr < 8; ++rr) {
        int orow = wg * 8 + rr;              // 0..2047 = d*4+g
        int d = orow >> 2, g = orow & 3;
        int col = g * DH + d;
        #pragma unroll
        for (int e = 0; e < 4; ++e) {
            int k = e * NTHR + tid;
            float v = (k < NID) ? Wf[(size_t)k * NG + col]
                                : Wr[(size_t)(k - NID) * NG + col];
            WT[(size_t)orow * KTOT + k] = (_Float16)v;
        }
    }
    int gtid = wg * NTHR + tid;              // 0..65535 == BATCH*DH
    if (gtid < NG) { int d = gtid >> 2, g = gtid & 3; bfa[gtid] = bfs[g * DH + d]; }
    hb[gtid]   = (_Float16)h0[gtid];         // buffer 0
    cbuf[gtid] = c0[gtid];
    grid.sync();

    // ---- resident recurrent-weight fragments (my 16 cols, k=512..1023) ----
    const int cgidx = wg & 127;              // col group: arranged cols [cg*16, cg*16+16)
    const int rh    = wg >> 7;               // batch half: rows [rh*64, rh*64+64)
    const int mycol = cgidx * 16 + l15;
    f16x8 Bres[16];
    #pragma unroll
    for (int s = 0; s < 16; ++s)
        Bres[s] = *(const f16x8*)(WT + (size_t)mycol * KTOT + NID + s * 32 + l4 * 8);

    for (int ck = 0; ck < NCHUNK; ++ck) {
        // ---- phase B: z = X*Wf + bf for this chunk (M=8192, K=512, N=2048) ----
        // tiles 64 rows x 64 cols: 128 rb x 32 cb; WG does 16 tiles.
        for (int it = 0; it < 16; ++it) {
            int tile = it * NWG + wg;
            int cb = tile & 31;
            int rb = tile >> 5;
            int mrow = rb * 64 + wv * 16 + l15;       // m in [0,8192)
            const float* xrow = X + ((size_t)ck * 8192 + mrow) * NID;
            f32x4 acc[4] = {{0.f,0.f,0.f,0.f},{0.f,0.f,0.f,0.f},
                            {0.f,0.f,0.f,0.f},{0.f,0.f,0.f,0.f}};
            #pragma unroll 4
            for (int s = 0; s < 16; ++s) {
                int k = s * 32 + l4 * 8;
                f32x4 x0 = *(const f32x4*)(xrow + k);
                f32x4 x1 = *(const f32x4*)(xrow + k + 4);
                f16x8 a;
                a[0]=(_Float16)x0[0]; a[1]=(_Float16)x0[1];
                a[2]=(_Float16)x0[2]; a[3]=(_Float16)x0[3];
                a[4]=(_Float16)x1[0]; a[5]=(_Float16)x1[1];
                a[6]=(_Float16)x1[2]; a[7]=(_Float16)x1[3];
                #pragma unroll
                for (int ct = 0; ct < 4; ++ct) {
                    f16x8 b = *(const f16x8*)(WT + (size_t)(cb*64 + ct*16 + l15) * KTOT + k);
                    acc[ct] = __builtin_amdgcn_mfma_f32_16x16x32_f16(a, b, acc[ct], 0, 0, 0);
                }
            }
            #pragma unroll
            for (int ct = 0; ct < 4; ++ct) {
                int col = cb * 64 + ct * 16 + l15;
                float bias = bfa[col];
                #pragma unroll
                for (int j = 0; j < 4; ++j) {
                    int row = rb * 64 + wv * 16 + l4 * 4 + j;
                    zbuf[(size_t)row * NG + col] = (_Float16)(acc[ct][j] + bias);
                }
            }
        }
        grid.sync();

        // ---- scan: 64 steps, recurrent GEMM from register-resident Wr ----
        for (int tc = 0; tc < TC; ++tc) {
            int t = ck * TC + tc;
            const _Float16* hin  = hb + (size_t)(t & 1) * (BATCH * DH);
            _Float16*       hout = hb + (size_t)((t + 1) & 1) * (BATCH * DH);

            int arow = rh * 64 + wv * 16 + l15;       // batch row for A-frag
            f32x4 acc = {0.f, 0.f, 0.f, 0.f};
            #pragma unroll
            for (int s = 0; s < 16; ++s) {
                f16x8 a = *(const f16x8*)(hin + (size_t)arow * DH + s * 32 + l4 * 8);
                acc = __builtin_amdgcn_mfma_f32_16x16x32_f16(a, Bres[s], acc, 0, 0, 0);
            }
            // add z, stage to LDS (wave-private region; same-wave dep -> no barrier)
            #pragma unroll
            for (int j = 0; j < 4; ++j) {
                int brow = rh * 64 + wv * 16 + l4 * 4 + j;
                float z = (float)zbuf[(size_t)(tc * BATCH + brow) * NG + cgidx * 16 + l15];
                zs[wv][l4 * 4 + j][l15] = acc[j] + z;
            }
            // gate phase: lane -> (rr = batch row within 16, dl = d within 4)
            int rr = lane >> 2, dl = lane & 3;
            int b  = rh * 64 + wv * 16 + rr;
            int d  = cgidx * 4 + dl;
            float z0 = zs[wv][rr][dl * 4 + 0];
            float z1 = zs[wv][rr][dl * 4 + 1];
            float z2 = zs[wv][rr][dl * 4 + 2];
            float z3 = zs[wv][rr][dl * 4 + 3];
            float cin = tanh_fast(z0);
            float ig  = sigmoid_fast(z1);
            float fg  = sigmoid_fast(z2);
            float og  = sigmoid_fast(z3);
            float mm   = imask[(size_t)t * BATCH + b];
            float cold = cbuf[b * DH + d];
            float cnew = mm * (cold * fg + cin * ig) + (1.0f - mm) * cold;
            float y    = mm * (og * tanh_fast(cnew));
            cbuf[b * DH + d] = cnew;
            size_t o = ((size_t)t * BATCH + b) * DH + d;
            Yout[o] = y;
            Cout[o] = cnew;
            hout[b * DH + d] = (_Float16)y;
            if (t == T_STEPS - 1) dout[b * DH + d] = cnew;
            grid.sync();
        }
    }
}

// ============================ fallback path (round-2, proven) ============================
__global__ void prep_weights(const float* __restrict__ Wf, const float* __restrict__ Wr,
                             const float* __restrict__ bf, _Float16* __restrict__ WT,
                             float* __restrict__ bfa) {
    int orow = blockIdx.x;
    int d = orow >> 2, g = orow & 3;
    int col = g * DH + d;
    for (int e = 0; e < 4; ++e) {
        int k = (e << 8) + threadIdx.x;
        float v = (k < NID) ? Wf[(size_t)k * NG + col] : Wr[(size_t)(k - NID) * NG + col];
        WT[(size_t)orow * KTOT + k] = (_Float16)v;
    }
    if (threadIdx.x == 0) bfa[orow] = bf[col];
}

__global__ void prep_state(const float* __restrict__ h0, const float* __restrict__ c0,
                           _Float16* __restrict__ h, float* __restrict__ c) {
    int base = blockIdx.x * 1024 + threadIdx.x;
    for (int e = 0; e < 4; ++e) {
        int i = base + e * 256;
        h[i] = (_Float16)h0[i];
        c[i] = c0[i];
    }
}

__global__ __launch_bounds__(256)
void lstm_step(const float* __restrict__ X, const float* __restrict__ imask,
               const _Float16* __restrict__ WT, const float* __restrict__ bfa,
               const _Float16* __restrict__ hin, _Float16* __restrict__ hout,
               float* __restrict__ c, float* __restrict__ Yout,
               float* __restrict__ Cout, float* __restrict__ dout, int t) {
    __shared__ float zsl[32][68];
    const int tid = threadIdx.x;
    const int lane = tid & 63, w = tid >> 6;
    const int l15 = lane & 15, l4 = lane >> 4;
    const int b0 = blockIdx.x * 32, gc0 = blockIdx.y * 64;
    const int rt = w & 1, ct0 = (w >> 1) * 2;
    const int arow = b0 + rt * 16 + l15;
    const float* xrow = X + ((size_t)t * BATCH + arow) * NID;
    const _Float16* hrow = hin + (size_t)arow * DH;
    const int koff = l4 * 8;
    const _Float16* bp0 = WT + (size_t)(gc0 + 16 * ct0 + l15) * KTOT + koff;
    const _Float16* bp1 = WT + (size_t)(gc0 + 16 * (ct0 + 1) + l15) * KTOT + koff;
    f32x4 acc0 = {0.f,0.f,0.f,0.f}, acc1 = {0.f,0.f,0.f,0.f};
    #pragma unroll 4
    for (int k0 = 0; k0 < KTOT; k0 += 32) {
        f16x8 a;
        if (k0 < NID) {
            const float* xp = xrow + k0 + koff;
            f32x4 v0 = *(const f32x4*)xp;
            f32x4 v1 = *(const f32x4*)(xp + 4);
            a[0]=(_Float16)v0[0]; a[1]=(_Float16)v0[1]; a[2]=(_Float16)v0[2]; a[3]=(_Float16)v0[3];
            a[4]=(_Float16)v1[0]; a[5]=(_Float16)v1[1]; a[6]=(_Float16)v1[2]; a[7]=(_Float16)v1[3];
        } else {
            a = *(const f16x8*)(hrow + (k0 - NID) + koff);
        }
        f16x8 bf0 = *(const f16x8*)(bp0 + k0);
        f16x8 bf1 = *(const f16x8*)(bp1 + k0);
        acc0 = __builtin_amdgcn_mfma_f32_16x16x32_f16(a, bf0, acc0, 0, 0, 0);
        acc1 = __builtin_amdgcn_mfma_f32_16x16x32_f16(a, bf1, acc1, 0, 0, 0);
    }
    #pragma unroll
    for (int rg = 0; rg < 4; ++rg) {
        int row = rt * 16 + l4 * 4 + rg;
        zsl[row][16 * ct0 + l15]       = acc0[rg];
        zsl[row][16 * (ct0 + 1) + l15] = acc1[rg];
    }
    __syncthreads();
    #pragma unroll
    for (int q = 0; q < 2; ++q) {
        int idx = q * 256 + tid;
        int r = idx >> 4, dl = idx & 15;
        int b = b0 + r, dglob = blockIdx.y * 16 + dl;
        f32x4 bb = *(const f32x4*)(bfa + gc0 + dl * 4);
        float z0 = zsl[r][dl*4+0] + bb[0];
        float z1 = zsl[r][dl*4+1] + bb[1];
        float z2 = zsl[r][dl*4+2] + bb[2];
        float z3 = zsl[r][dl*4+3] + bb[3];
        float cin = tanh_fast(z0), ig = sigmoid_fast(z1);
        float fg = sigmoid_fast(z2), og = sigmoid_fast(z3);
        float m = imask[(size_t)t * BATCH + b];
        float cold = c[b * DH + dglob];
        float cnew = m * (cold * fg + cin * ig) + (1.0f - m) * cold;
        float y = m * (og * tanh_fast(cnew));
        size_t oidx = ((size_t)t * BATCH + b) * DH + dglob;
        Yout[oidx] = y; Cout[oidx] = cnew;
        c[b * DH + dglob] = cnew;
        hout[b * DH + dglob] = (_Float16)y;
        if (t == T_STEPS - 1) dout[b * DH + dglob] = cnew;
    }
}

// ============================ launch ============================
extern "C" void kernel_launch(void* const* d_in, const int* in_sizes, int n_in,
                              void* d_out, int out_size, void* d_ws, size_t ws_size,
                              hipStream_t stream) {
    const float* X  = (const float*)d_in[0];
    const float* Wf = (const float*)d_in[1];
    const float* Wr = (const float*)d_in[2];
    const float* bf = (const float*)d_in[3];
    const float* im = (const float*)d_in[4];
    const float* h0 = (const float*)d_in[5];
    const float* c0 = (const float*)d_in[6];

    char* ws = (char*)d_ws;
    _Float16* WT   = (_Float16*)ws;                                   // 4 MB
    float*    bfa  = (float*)(ws + (4u << 20));                       // 8 KB
    _Float16* hb   = (_Float16*)(ws + (4u << 20) + 8192);             // 256 KB (2 buffers)
    float*    cbuf = (float*)(ws + (4u << 20) + 8192 + 262144);       // 256 KB
    _Float16* zbuf = (_Float16*)(ws + (8u << 20));                    // 32 MB

    float* Yout = (float*)d_out;
    float* Cout = Yout + (size_t)T_STEPS * BATCH * DH;
    float* dout = Cout + (size_t)T_STEPS * BATCH * DH;

    bool coop_ok = ws_size >= ((8u << 20) + (size_t)TC * BATCH * NG * sizeof(_Float16));
    if (coop_ok) {
        void* args[] = {(void*)&X, (void*)&Wf, (void*)&Wr, (void*)&bf, (void*)&im,
                        (void*)&h0, (void*)&c0, (void*)&WT, (void*)&bfa, (void*)&hb,
                        (void*)&cbuf, (void*)&zbuf, (void*)&Yout, (void*)&Cout, (void*)&dout};
        hipError_t e = hipLaunchCooperativeKernel((void*)lstm_persist, dim3(NWG), dim3(NTHR),
                                                  args, 0, stream);
        if (e == hipSuccess) return;
    }
    // fallback: proven per-step path
    hipLaunchKernelGGL(prep_weights, dim3(2048), dim3(256), 0, stream, Wf, Wr, bf, WT, bfa);
    _Float16* hb0 = hb;
    _Float16* hb1 = hb + BATCH * DH;
    hipLaunchKernelGGL(prep_state, dim3(64), dim3(256), 0, stream, h0, c0, hb0, cbuf);
    for (int t = 0; t < T_STEPS; ++t) {
        const _Float16* hin = (t & 1) ? hb1 : hb0;
        _Float16*      hout = (t & 1) ? hb0 : hb1;
        hipLaunchKernelGGL(lstm_step, dim3(4, 32), dim3(256), 0, stream,
                           X, im, WT, bfa, hin, hout, cbuf, Yout, Cout, dout, t);
    }
}